// Round 15
// baseline (619.437 us; speedup 1.0000x reference)
//
#include <hip/hip_runtime.h>
#include <hip/hip_bf16.h>

#define N_NODES 50000
#define E_EDGES 200000
static constexpr float INV_SQRT_C = 0.08838834764831845f; // 1/sqrt(128)
static constexpr int NB_NODE = ((N_NODES + 63) / 64) * 4;  // 3128
static constexpr int NB_EDGE = E_EDGES / 64;               // 3125
static constexpr int NB_PAIR = 2 * NB_EDGE;                // 6250 interleaved
static constexpr int NB_FUSED = NB_NODE + NB_EDGE;         // 6253
static constexpr int NB_PREP = 40;
static constexpr int NB_CONV = 12500;
static constexpr int NB_CNT  = ((E_EDGES + 255) / 256) * 2; // 1564
static constexpr int AGG_BLOCKS_MEGA = 1536;               // agg blocks inside mega_ea
static constexpr int NB_MEGA_EA = 3 * AGG_BLOCKS_MEGA + (NB_EDGE - 2 * AGG_BLOCKS_MEGA); // 4661

typedef __attribute__((ext_vector_type(4))) float f32x4;
typedef __attribute__((ext_vector_type(8))) short s16x8;
typedef __attribute__((ext_vector_type(4))) short s16x4;

__device__ __forceinline__ float b2f(unsigned short u) {
  union { unsigned u; float f; } x; x.u = ((unsigned)u) << 16; return x.f;
}
__device__ __forceinline__ short f2b(float f) {
  union { float f; unsigned u; } x; x.f = f;
  unsigned r = x.u + 0x7FFFu + ((x.u >> 16) & 1u);  // RNE
  return (short)(r >> 16);
}

struct WPtrs { const float* w[10]; };

struct NodeSet {
  const unsigned short* X16[4];
  const float* Xf[4];
  const short* Wt[4];
  const float* bias[4];
  unsigned short* o16[4];
  float* of[4];
};
struct EdgeSet {
  const int* ei; const float* tvec; const float* lu; const float* msg;
  const short* WeT; const int* pos; unsigned short* e16g;
};

// ---------------- device bodies (round-13/14 proven) ----------------
__device__ __forceinline__ void node_block(char* smem, int tid, int nb,
                                           const NodeSet& N, int use16) {
  short* As = (short*)smem;
  const int l = tid & 63;
  const int w = tid >> 6;
  const int colb = l & 15;
  const int g = l >> 4;
  const int job = nb / 782;
  const int m0 = (nb - job * 782) * 64;
  const bool fullblk = (m0 + 64 <= N_NODES);
  const short* Wt = N.Wt[job];
  const float* bias = N.bias[job];
  unsigned short* o16 = N.o16[job];
  float* of = N.of[job];

  if (use16) {
    const unsigned short* X = N.X16[job];
    if (fullblk) {
#pragma unroll
      for (int i = 0; i < 4; ++i) {
        int flat = tid + i * 512;
        int r = flat >> 5, cg = flat & 31;
        *(s16x8*)&As[r * 264 + cg * 8] = *(const s16x8*)(X + (size_t)(m0 + r) * 256 + cg * 8);
      }
    } else {
#pragma unroll
      for (int i = 0; i < 4; ++i) {
        int flat = tid + i * 512;
        int r = flat >> 5, cg = flat & 31;
        s16x8 v = (s16x8)(short)0;
        if (m0 + r < N_NODES) v = *(const s16x8*)(X + (size_t)(m0 + r) * 256 + cg * 8);
        *(s16x8*)&As[r * 264 + cg * 8] = v;
      }
    }
  } else {
    const float* X = N.Xf[job];
#pragma unroll
    for (int i = 0; i < 8; ++i) {
      int flat = tid + i * 512;
      int r = flat >> 6, c4 = flat & 63;
      float4 xv = make_float4(0.f, 0.f, 0.f, 0.f);
      if (fullblk || m0 + r < N_NODES) xv = *(const float4*)(X + (size_t)(m0 + r) * 256 + c4 * 4);
      s16x4 sv; sv[0] = f2b(xv.x); sv[1] = f2b(xv.y); sv[2] = f2b(xv.z); sv[3] = f2b(xv.w);
      *(s16x4*)&As[r * 264 + c4 * 4] = sv;
    }
  }
  __syncthreads();

  const short* wbase0 = Wt + (((2 * w + 0) * 8) * 16 + colb) * 32 + g * 8;
  const short* wbase1 = Wt + (((2 * w + 1) * 8) * 16 + colb) * 32 + g * 8;

  f32x4 acc[4][2];
#pragma unroll
  for (int m = 0; m < 4; ++m) { acc[m][0] = (f32x4)(0.0f); acc[m][1] = (f32x4)(0.0f); }
#pragma unroll
  for (int ks = 0; ks < 8; ++ks) {
    s16x8 b0 = *(const s16x8*)(wbase0 + ks * 512);
    s16x8 b1 = *(const s16x8*)(wbase1 + ks * 512);
#pragma unroll
    for (int m = 0; m < 4; ++m) {
      s16x8 a = *(const s16x8*)&As[(16 * m + colb) * 264 + ks * 32 + g * 8];
      acc[m][0] = __builtin_amdgcn_mfma_f32_16x16x32_bf16(a, b0, acc[m][0], 0, 0, 0);
      acc[m][1] = __builtin_amdgcn_mfma_f32_16x16x32_bf16(a, b1, acc[m][1], 0, 0, 0);
    }
  }
  __syncthreads();   // done with As data

  if (of) {          // f32 output: bounce 32 rows at a time
    float* buf = (float*)smem;
#pragma unroll 1
    for (int half = 0; half < 2; ++half) {
#pragma unroll
      for (int j = 0; j < 2; ++j) {
        int col = (2 * w + j) * 16 + colb;
        float bv = bias[col];
#pragma unroll
        for (int mm = 0; mm < 2; ++mm) {
          int m = half * 2 + mm;
#pragma unroll
          for (int r = 0; r < 4; ++r)
            buf[(16 * mm + g * 4 + r) * 260 + col] = acc[m][j][r] + bv;
        }
      }
      __syncthreads();
#pragma unroll
      for (int i = 0; i < 4; ++i) {
        int flat = tid + i * 512;
        int row = flat >> 6, ch = flat & 63;
        int grow = m0 + half * 32 + row;
        if (fullblk || grow < N_NODES)
          *(float4*)(of + (size_t)grow * 256 + ch * 4) = *(const float4*)&buf[row * 260 + ch * 4];
      }
      __syncthreads();
    }
  } else {           // bf16 output: full 64-row bounce
    short* buf = (short*)smem;
#pragma unroll
    for (int j = 0; j < 2; ++j) {
      int col = (2 * w + j) * 16 + colb;
      float bv = bias[col];
#pragma unroll
      for (int m = 0; m < 4; ++m)
#pragma unroll
        for (int r = 0; r < 4; ++r)
          buf[(16 * m + g * 4 + r) * 264 + col] = f2b(acc[m][j][r] + bv);
    }
    __syncthreads();
#pragma unroll
    for (int i = 0; i < 4; ++i) {
      int flat = tid + i * 512;
      int row = flat >> 5, ch = flat & 31;
      if (fullblk || m0 + row < N_NODES)
        *(s16x8*)(o16 + (size_t)(m0 + row) * 256 + ch * 8) = *(const s16x8*)&buf[row * 264 + ch * 8];
    }
  }
}

__device__ __forceinline__ void edge_block(char* smem, int tid, int eb,
                                           const EdgeSet& E,
                                           const float* Wtim, const float* btim) {
  short* attr = (short*)smem;                       // 64*264 bf16 = 33792 B
  float* rel  = (float*)(smem + 33792);             // 256 B
  int*   poss = (int*)(smem + 34048);               // 256 B
  const int l = tid & 63;
  const int w = tid >> 6;
  const int colb = l & 15;
  const int g = l >> 4;
  const int e0 = eb * 64;

  const float wt = Wtim[tid & 127], bt = btim[tid & 127];

  if (tid < 64) {
    rel[tid] = E.tvec[e0 + tid] - E.lu[E.ei[e0 + tid]];
    poss[tid] = E.pos[e0 + tid];
  }
#pragma unroll
  for (int i = 0; i < 4; ++i) {
    int flat = tid + i * 512;
    int row = flat >> 5, c4 = flat & 31;
    float4 mv = *(const float4*)(E.msg + (size_t)(e0 + row) * 128 + c4 * 4);
    s16x4 sv; sv[0] = f2b(mv.x); sv[1] = f2b(mv.y); sv[2] = f2b(mv.z); sv[3] = f2b(mv.w);
    *(s16x4*)&attr[row * 264 + 128 + c4 * 4] = sv;
  }
  __syncthreads();   // rel + msg staged

  { // time-encoder cols
    int col = tid & 127;
    int r0 = (tid >> 7) * 16;
#pragma unroll
    for (int i = 0; i < 16; ++i)
      attr[(r0 + i) * 264 + col] = f2b(__cosf(rel[r0 + i] * wt + bt));
  }
  __syncthreads();

  const short* wbase0 = E.WeT + (((2 * w + 0) * 8) * 16 + colb) * 32 + g * 8;
  const short* wbase1 = E.WeT + (((2 * w + 1) * 8) * 16 + colb) * 32 + g * 8;
  f32x4 acc[4][2];
#pragma unroll
  for (int m = 0; m < 4; ++m) { acc[m][0] = (f32x4)(0.0f); acc[m][1] = (f32x4)(0.0f); }
#pragma unroll
  for (int ks = 0; ks < 8; ++ks) {
    s16x8 b0 = *(const s16x8*)(wbase0 + ks * 512);
    s16x8 b1 = *(const s16x8*)(wbase1 + ks * 512);
#pragma unroll
    for (int m = 0; m < 4; ++m) {
      s16x8 a = *(const s16x8*)&attr[(16 * m + colb) * 264 + ks * 32 + g * 8];
      acc[m][0] = __builtin_amdgcn_mfma_f32_16x16x32_bf16(a, b0, acc[m][0], 0, 0, 0);
      acc[m][1] = __builtin_amdgcn_mfma_f32_16x16x32_bf16(a, b1, acc[m][1], 0, 0, 0);
    }
  }
  __syncthreads();   // all waves done reading attr
#pragma unroll
  for (int j = 0; j < 2; ++j)
#pragma unroll
    for (int m = 0; m < 4; ++m)
#pragma unroll
      for (int r = 0; r < 4; ++r)
        attr[(16 * m + g * 4 + r) * 264 + (2 * w + j) * 16 + colb] = f2b(acc[m][j][r]);
  __syncthreads();

#pragma unroll
  for (int i = 0; i < 4; ++i) {
    int flat = tid + i * 512;
    int row = flat >> 5, cg = flat & 31;
    size_t slot = (size_t)poss[row];
    *(s16x8*)(E.e16g + slot * 256 + cg * 8) = *(const s16x8*)&attr[row * 264 + cg * 8];
  }
}

// per-dst aggregate body (proven, 4-way ILP)
__device__ __forceinline__ void process_dst(
    int d, int c0, const int* __restrict__ start, const unsigned short* __restrict__ esrc,
    const unsigned short* __restrict__ Q16, const unsigned short* __restrict__ K16,
    const unsigned short* __restrict__ V16, const unsigned short* __restrict__ e16,
    float* __restrict__ out)
{
  const int s0 = start[d], s1 = start[d + 1];
  if (s1 <= s0) return;

  s16x4 qv = *(const s16x4*)(Q16 + (size_t)d * 256 + c0);
  const float q0 = b2f((unsigned short)qv[0]), q1 = b2f((unsigned short)qv[1]);
  const float q2 = b2f((unsigned short)qv[2]), q3 = b2f((unsigned short)qv[3]);

  float den = 0.f;
  float a0 = 0.f, a1 = 0.f, a2 = 0.f, a3 = 0.f;
  int p = s0;

#define EDGE_LOAD(J, PP)                                                    \
    int s##J = (int)esrc[PP];                                               \
    s16x4 ev##J = *(const s16x4*)(e16 + (size_t)(PP) * 256 + c0);           \
    s16x4 kv##J = *(const s16x4*)(K16 + (size_t)s##J * 256 + c0);           \
    s16x4 vv##J = *(const s16x4*)(V16 + (size_t)s##J * 256 + c0);           \
    float e0##J = b2f((unsigned short)ev##J[0]), e1##J = b2f((unsigned short)ev##J[1]); \
    float e2##J = b2f((unsigned short)ev##J[2]), e3##J = b2f((unsigned short)ev##J[3]); \
    float dt##J = q0 * (b2f((unsigned short)kv##J[0]) + e0##J)              \
                + q1 * (b2f((unsigned short)kv##J[1]) + e1##J)              \
                + q2 * (b2f((unsigned short)kv##J[2]) + e2##J)              \
                + q3 * (b2f((unsigned short)kv##J[3]) + e3##J);

#define EDGE_ACC(J)                                                         \
    den += ex##J;                                                           \
    a0 += ex##J * (b2f((unsigned short)vv##J[0]) + e0##J);                  \
    a1 += ex##J * (b2f((unsigned short)vv##J[1]) + e1##J);                  \
    a2 += ex##J * (b2f((unsigned short)vv##J[2]) + e2##J);                  \
    a3 += ex##J * (b2f((unsigned short)vv##J[3]) + e3##J);

  for (; p + 4 <= s1; p += 4) {
    EDGE_LOAD(A, p)  EDGE_LOAD(B, p + 1)  EDGE_LOAD(C, p + 2)  EDGE_LOAD(D, p + 3)
    dtA += __shfl_xor(dtA, 1);  dtB += __shfl_xor(dtB, 1);
    dtC += __shfl_xor(dtC, 1);  dtD += __shfl_xor(dtD, 1);
    dtA += __shfl_xor(dtA, 2);  dtB += __shfl_xor(dtB, 2);
    dtC += __shfl_xor(dtC, 2);  dtD += __shfl_xor(dtD, 2);
    dtA += __shfl_xor(dtA, 4);  dtB += __shfl_xor(dtB, 4);
    dtC += __shfl_xor(dtC, 4);  dtD += __shfl_xor(dtD, 4);
    dtA += __shfl_xor(dtA, 8);  dtB += __shfl_xor(dtB, 8);
    dtC += __shfl_xor(dtC, 8);  dtD += __shfl_xor(dtD, 8);
    dtA += __shfl_xor(dtA, 16); dtB += __shfl_xor(dtB, 16);
    dtC += __shfl_xor(dtC, 16); dtD += __shfl_xor(dtD, 16);
    float exA = __expf(dtA * INV_SQRT_C), exB = __expf(dtB * INV_SQRT_C);
    float exC = __expf(dtC * INV_SQRT_C), exD = __expf(dtD * INV_SQRT_C);
    EDGE_ACC(A) EDGE_ACC(B) EDGE_ACC(C) EDGE_ACC(D)
  }
  for (; p < s1; ++p) {
    EDGE_LOAD(T, p)
    dtT += __shfl_xor(dtT, 1);
    dtT += __shfl_xor(dtT, 2);
    dtT += __shfl_xor(dtT, 4);
    dtT += __shfl_xor(dtT, 8);
    dtT += __shfl_xor(dtT, 16);
    float exT = __expf(dtT * INV_SQRT_C);
    EDGE_ACC(T)
  }
#undef EDGE_LOAD
#undef EDGE_ACC

  float inv = 1.f / (den + 1e-16f);
  float4* op = (float4*)(out + (size_t)d * 256 + c0);
  float4 o = *op;
  o.x += a0 * inv; o.y += a1 * inv; o.z += a2 * inv; o.w += a3 * inv;
  *op = o;
}

// ---------------- setup: prep_transpose + conv_x + csr_count fused ----------
__global__ __launch_bounds__(256) void setup_fused(
    WPtrs p, short* __restrict__ WtT,
    const float* __restrict__ xu, const float* __restrict__ xi,
    unsigned short* __restrict__ x16u, unsigned short* __restrict__ x16i, int nconv,
    const int* __restrict__ eia, const int* __restrict__ eib, int* __restrict__ counts)
{
  __shared__ short T[256 * 66];
  const int bx = blockIdx.x;
  const int tid = threadIdx.x;

  if (bx < NB_PREP) {
    const int wi = bx >> 2, cq = bx & 3;
    const float* w = p.w[wi];
    short* o = WtT + wi * 65536;
#pragma unroll
    for (int i = 0; i < 64; ++i) {
      int flat = tid + i * 256;
      int k = flat >> 6, cc = flat & 63;
      T[k * 66 + cc] = f2b(w[k * 256 + cq * 64 + cc]);
    }
    __syncthreads();
#pragma unroll
    for (int i = 0; i < 8; ++i) {
      int flat2 = tid + i * 256;
      int g = flat2 & 3, colb = (flat2 >> 2) & 15, ks = (flat2 >> 6) & 7, ctl = flat2 >> 9;
      int ct = cq * 4 + ctl;
      s16x8 v;
#pragma unroll
      for (int j = 0; j < 8; ++j)
        v[j] = T[(ks * 32 + g * 8 + j) * 66 + ctl * 16 + colb];
      *(s16x8*)(o + (((ct * 8 + ks) * 16 + colb) * 32 + g * 8)) = v;
    }
    return;
  }
  int cb = bx - NB_PREP;
  if (cb < nconv) {                    // conv_x
    int y = cb >= (nconv / 2);
    int xb = y ? cb - nconv / 2 : cb;
    const float* in = y ? xi : xu;
    unsigned short* out = y ? x16i : x16u;
    size_t base = ((size_t)xb * 256 + tid) * 8;
    float4 a = *(const float4*)(in + base);
    float4 b = *(const float4*)(in + base + 4);
    s16x8 v;
    v[0] = f2b(a.x); v[1] = f2b(a.y); v[2] = f2b(a.z); v[3] = f2b(a.w);
    v[4] = f2b(b.x); v[5] = f2b(b.y); v[6] = f2b(b.z); v[7] = f2b(b.w);
    *(s16x8*)(out + base) = v;
    return;
  }
  cb -= nconv;                         // csr_count
  int y = cb >= (NB_CNT / 2);
  int tb = y ? cb - NB_CNT / 2 : cb;
  const int* ei = y ? eib : eia;
  int* c = counts + y * N_NODES;
  int t = tb * 256 + tid;
  if (t < E_EDGES) atomicAdd(&c[ei[E_EDGES + t]], 1);
}

// ---------------- CSR scan / fill ----------------
__global__ __launch_bounds__(1024) void csr_scan2(int* __restrict__ counts,
                                                  int* __restrict__ start) {
  int* cnt = counts + blockIdx.x * N_NODES;
  int* st  = start + blockIdx.x * (N_NODES + 1);
  __shared__ int wsum[16];
  __shared__ int chunk_tot;
  __shared__ int carry_s;
  const int tid = threadIdx.x, lane = tid & 63, wid = tid >> 6;
  if (tid == 0) carry_s = 0;
  __syncthreads();
  for (int base = 0; base < N_NODES; base += 1024) {
    int gi = base + tid;
    int x = (gi < N_NODES) ? cnt[gi] : 0;
    int v = x;
#pragma unroll
    for (int d = 1; d < 64; d <<= 1) {
      int t = __shfl_up(v, d);
      if (lane >= d) v += t;
    }
    if (lane == 63) wsum[wid] = v;
    __syncthreads();
    if (tid == 0) {
      int run = 0;
#pragma unroll
      for (int i = 0; i < 16; ++i) { int t = wsum[i]; wsum[i] = run; run += t; }
      chunk_tot = run;
    }
    __syncthreads();
    if (gi < N_NODES) {
      int excl = carry_s + wsum[wid] + v - x;
      st[gi] = excl;
      cnt[gi] = excl;       // becomes the fill cursor
    }
    __syncthreads();
    if (tid == 0) carry_s += chunk_tot;
  }
  if (tid == 0) st[N_NODES] = carry_s;
}

__global__ __launch_bounds__(256) void csr_fill2(const int* __restrict__ eia,
                                                 const int* __restrict__ eib,
                                                 int* __restrict__ counts,
                                                 int* __restrict__ pos,
                                                 unsigned short* __restrict__ esrc) {
  int t = blockIdx.x * 256 + threadIdx.x;
  const int* ei = blockIdx.y ? eib : eia;
  int* cur = counts + blockIdx.y * N_NODES;
  int* ps  = pos + blockIdx.y * E_EDGES;
  unsigned short* es = esrc + (size_t)blockIdx.y * E_EDGES;
  if (t < E_EDGES) {
    int d = ei[E_EDGES + t];
    int p = atomicAdd(&cur[d], 1);
    ps[t] = p;
    es[p] = (unsigned short)ei[t];
  }
}

// ---------------- fused node+edge: single type ----------------
struct FusedArgs { NodeSet n; EdgeSet e; const float* Wtim; const float* btim; int use16; };

__global__ __launch_bounds__(512) void fused_ne(FusedArgs A) {
  __shared__ __align__(16) char smem[34816];
  const int bx = blockIdx.x;
  int nb = -1, eb = -1;
  if (bx < NB_PAIR) { if (bx & 1) eb = bx >> 1; else nb = bx >> 1; }
  else nb = NB_EDGE + (bx - NB_PAIR);
  if (nb >= 0) node_block(smem, threadIdx.x, nb, A.n, A.use16);
  else         edge_block(smem, threadIdx.x, eb, A.e, A.Wtim, A.btim);
}

// ---------------- node-only dispatch (type b nodes in T2e) ----------------
__global__ __launch_bounds__(512) void node_only(NodeSet N, int use16) {
  __shared__ __align__(16) char smem[34816];
  node_block(smem, threadIdx.x, blockIdx.x, N, use16);
}

// ---------------- mega_ea: edge_b || agg_a in one dispatch (T2e) ----------
struct MegaEA {
  EdgeSet e;                        // type b edge -> e16b
  const float* Wtim; const float* btim;
  const int* start; const unsigned short* esrc;   // type a CSR
  const unsigned short* Q; const unsigned short* K;
  const unsigned short* V; const unsigned short* e16;   // type a tables
  float* out;                       // out_item
};

__global__ __launch_bounds__(512) void mega_ea(MegaEA M) {
  __shared__ __align__(16) char smem[34816];
  const int bx = blockIdx.x;
  int eb = -1, ab = -1;
  if (bx < 3 * AGG_BLOCKS_MEGA) {   // groups of 3: 2 edge + 1 agg
    int gp = bx / 3, r = bx - gp * 3;
    if (r < 2) eb = gp * 2 + r; else ab = gp;
  } else {
    eb = 2 * AGG_BLOCKS_MEGA + (bx - 3 * AGG_BLOCKS_MEGA);
  }
  if (eb >= 0) {
    edge_block(smem, threadIdx.x, eb, M.e, M.Wtim, M.btim);
  } else {
    const int wave = ab * 8 + (threadIdx.x >> 6);
    const int nwaves = AGG_BLOCKS_MEGA * 8;
    const int c0 = (threadIdx.x & 63) * 4;
    for (int d = wave; d < N_NODES; d += nwaves)
      process_dst(d, c0, M.start, M.esrc, M.Q, M.K, M.V, M.e16, M.out);
  }
}

// ---------------- standalone aggregate (persistent waves) ----------------
__global__ __launch_bounds__(256) void aggregate_fused5(
    const int* __restrict__ start, const unsigned short* __restrict__ esrc,
    const unsigned short* __restrict__ Q16, const unsigned short* __restrict__ K16,
    const unsigned short* __restrict__ V16, const unsigned short* __restrict__ e16,
    float* __restrict__ out)
{
  const int wave = blockIdx.x * 4 + (threadIdx.x >> 6);
  const int nwaves = gridDim.x * 4;
  const int c0 = (threadIdx.x & 63) * 4;
  for (int d = wave; d < N_NODES; d += nwaves)
    process_dst(d, c0, start, esrc, Q16, K16, V16, e16, out);
}

extern "C" void kernel_launch(void* const* d_in, const int* in_sizes, int n_in,
                              void* d_out, int out_size, void* d_ws, size_t ws_size,
                              hipStream_t stream) {
  const float* x_user  = (const float*)d_in[0];
  const float* x_item  = (const float*)d_in[1];
  const float* lu_user = (const float*)d_in[2];
  const float* lu_item = (const float*)d_in[3];
  const int*   ei_a    = (const int*)d_in[4];
  const int*   ei_b    = (const int*)d_in[5];
  const float* t_a     = (const float*)d_in[6];
  const float* t_b     = (const float*)d_in[7];
  const float* msg_a   = (const float*)d_in[8];
  const float* msg_b   = (const float*)d_in[9];
  const float* W_t     = (const float*)d_in[10];
  const float* b_t     = (const float*)d_in[11];
  const float* Wq_a = (const float*)d_in[12]; const float* bq_a = (const float*)d_in[13];
  const float* Wk_a = (const float*)d_in[14]; const float* bk_a = (const float*)d_in[15];
  const float* Wv_a = (const float*)d_in[16]; const float* bv_a = (const float*)d_in[17];
  const float* We_a = (const float*)d_in[18];
  const float* Ws_a = (const float*)d_in[19]; const float* bs_a = (const float*)d_in[20];
  const float* Wq_b = (const float*)d_in[21]; const float* bq_b = (const float*)d_in[22];
  const float* Wk_b = (const float*)d_in[23]; const float* bk_b = (const float*)d_in[24];
  const float* Wv_b = (const float*)d_in[25]; const float* bv_b = (const float*)d_in[26];
  const float* We_b = (const float*)d_in[27];
  const float* Ws_b = (const float*)d_in[28]; const float* bs_b = (const float*)d_in[29];

  float* out_user = (float*)d_out;
  float* out_item = (float*)d_out + (size_t)N_NODES * 256;

  WPtrs wp;
  wp.w[0] = Wq_a; wp.w[1] = Wk_a; wp.w[2] = Wv_a; wp.w[3] = Ws_a; wp.w[4] = We_a;
  wp.w[5] = Wq_b; wp.w[6] = Wk_b; wp.w[7] = Wv_b; wp.w[8] = Ws_b; wp.w[9] = We_b;

  dim3 blk(256);
  dim3 blk512(512);
  dim3 gEt2((E_EDGES + 255) / 256, 2);

  // ws layout
  char* ws = (char*)d_ws;
  size_t off = 0;
  short* WtT = (short*)(ws + off); off += (size_t)10 * 65536 * 2;
  unsigned short* Q16 = (unsigned short*)(ws + off); off += (size_t)N_NODES * 256 * 2;
  unsigned short* K16 = (unsigned short*)(ws + off); off += (size_t)N_NODES * 256 * 2;
  unsigned short* V16 = (unsigned short*)(ws + off); off += (size_t)N_NODES * 256 * 2;
  unsigned short* e16a = (unsigned short*)(ws + off); off += (size_t)E_EDGES * 256 * 2;
  int* pos    = (int*)(ws + off); off += (size_t)2 * E_EDGES * 4;
  int* counts = (int*)(ws + off); off += (size_t)2 * N_NODES * 4;
  int* startb = (int*)(ws + off); off += (size_t)2 * (N_NODES + 1) * 4;
  unsigned short* esrc = (unsigned short*)(ws + off); off += (size_t)2 * E_EDGES * 2;
  const size_t off_base = off;
  unsigned short* X16u = (unsigned short*)(ws + off); off += (size_t)N_NODES * 256 * 2;
  unsigned short* X16i = (unsigned short*)(ws + off); off += (size_t)N_NODES * 256 * 2;
  const size_t off_t1 = off;
  unsigned short* e16b = (unsigned short*)(ws + off); off += (size_t)E_EDGES * 256 * 2;
  const size_t off_t2e = off;
  const bool use_x16 = (ws_size >= off_t1);
  const bool use_t2e = (ws_size >= off_t2e);
  if (!use_x16 && ws_size < off_base) return;   // fail loudly

  const int nconv = use_x16 ? NB_CONV : 0;

  hipMemsetAsync(counts, 0, (size_t)2 * N_NODES * 4, stream);
  setup_fused<<<dim3(NB_PREP + nconv + NB_CNT), blk, 0, stream>>>(
      wp, WtT, x_user, x_item, X16u, X16i, nconv, ei_a, ei_b, counts);
  csr_scan2<<<2, 1024, 0, stream>>>(counts, startb);
  csr_fill2<<<gEt2, blk, 0, stream>>>(ei_a, ei_b, counts, pos, esrc);

  // Build per-type sets
  NodeSet na, nb_;
  na.X16[0] = X16u; na.X16[1] = X16u; na.X16[2] = X16i; na.X16[3] = X16i;
  na.Xf[0] = x_user; na.Xf[1] = x_user; na.Xf[2] = x_item; na.Xf[3] = x_item;
  na.Wt[0] = WtT + 1 * 65536; na.Wt[1] = WtT + 2 * 65536;
  na.Wt[2] = WtT + 0 * 65536; na.Wt[3] = WtT + 3 * 65536;
  na.bias[0] = bk_a; na.bias[1] = bv_a; na.bias[2] = bq_a; na.bias[3] = bs_a;
  na.o16[0] = K16; na.o16[1] = V16; na.o16[2] = Q16; na.o16[3] = nullptr;
  na.of[0] = nullptr; na.of[1] = nullptr; na.of[2] = nullptr; na.of[3] = out_item;

  nb_.X16[0] = X16i; nb_.X16[1] = X16i; nb_.X16[2] = X16u; nb_.X16[3] = X16u;
  nb_.Xf[0] = x_item; nb_.Xf[1] = x_item; nb_.Xf[2] = x_user; nb_.Xf[3] = x_user;
  nb_.Wt[0] = WtT + 6 * 65536; nb_.Wt[1] = WtT + 7 * 65536;
  nb_.Wt[2] = WtT + 5 * 65536; nb_.Wt[3] = WtT + 8 * 65536;
  nb_.bias[0] = bk_b; nb_.bias[1] = bv_b; nb_.bias[2] = bq_b; nb_.bias[3] = bs_b;
  nb_.o16[0] = K16; nb_.o16[1] = V16; nb_.o16[2] = Q16; nb_.o16[3] = nullptr;
  nb_.of[0] = nullptr; nb_.of[1] = nullptr; nb_.of[2] = nullptr; nb_.of[3] = out_user;

  EdgeSet ea, eb_;
  ea.ei = ei_a; ea.tvec = t_a; ea.lu = lu_user; ea.msg = msg_a;
  ea.WeT = WtT + 4 * 65536; ea.pos = pos; ea.e16g = e16a;
  eb_.ei = ei_b; eb_.tvec = t_b; eb_.lu = lu_item; eb_.msg = msg_b;
  eb_.WeT = WtT + 9 * 65536; eb_.pos = pos + E_EDGES;
  eb_.e16g = use_t2e ? e16b : e16a;

  const int u16 = use_x16 ? 1 : 0;

  // ---- type a: fused node+edge ----
  FusedArgs Aa; Aa.n = na; Aa.e = ea; Aa.Wtim = W_t; Aa.btim = b_t; Aa.use16 = u16;
  fused_ne<<<dim3(NB_FUSED), blk512, 0, stream>>>(Aa);

  if (use_t2e) {
    // edge_b (e16b) runs concurrently with agg_a (reads QKV, e16a)
    MegaEA M;
    M.e = eb_; M.Wtim = W_t; M.btim = b_t;
    M.start = startb; M.esrc = esrc;
    M.Q = Q16; M.K = K16; M.V = V16; M.e16 = e16a; M.out = out_item;
    mega_ea<<<dim3(NB_MEGA_EA), blk512, 0, stream>>>(M);
    // type b nodes (QKV reuse is safe: agg_a complete)
    node_only<<<dim3(NB_NODE), blk512, 0, stream>>>(nb_, u16);
    aggregate_fused5<<<dim3(2048), blk, 0, stream>>>(startb + (N_NODES + 1), esrc + E_EDGES,
        Q16, K16, V16, e16b, out_user);
  } else {
    aggregate_fused5<<<dim3(2048), blk, 0, stream>>>(startb, esrc, Q16, K16, V16, e16a, out_item);
    FusedArgs Ab; Ab.n = nb_; Ab.e = eb_; Ab.Wtim = W_t; Ab.btim = b_t; Ab.use16 = u16;
    fused_ne<<<dim3(NB_FUSED), blk512, 0, stream>>>(Ab);
    aggregate_fused5<<<dim3(2048), blk, 0, stream>>>(startb + (N_NODES + 1), esrc + E_EDGES,
        Q16, K16, V16, e16a, out_user);
  }
}

// Round 16
// 570.975 us; speedup vs baseline: 1.0849x; 1.0849x over previous
//
#include <hip/hip_runtime.h>
#include <hip/hip_bf16.h>

#define N_NODES 50000
#define E_EDGES 200000
static constexpr float INV_SQRT_C = 0.08838834764831845f; // 1/sqrt(128)
static constexpr int NB_NODE = ((N_NODES + 63) / 64) * 4;  // 3128
static constexpr int NB_EDGE = E_EDGES / 64;               // 3125
static constexpr int NB_PAIR = 2 * NB_EDGE;                // 6250 interleaved
static constexpr int NB_FUSED = NB_NODE + NB_EDGE;         // 6253
static constexpr int NB_PREP = 40;
static constexpr int NB_CONV = 12500;
static constexpr int NB_CNT  = ((E_EDGES + 255) / 256) * 2; // 1564

typedef __attribute__((ext_vector_type(4))) float f32x4;
typedef __attribute__((ext_vector_type(8))) short s16x8;
typedef __attribute__((ext_vector_type(4))) short s16x4;

__device__ __forceinline__ float b2f(unsigned short u) {
  union { unsigned u; float f; } x; x.u = ((unsigned)u) << 16; return x.f;
}
__device__ __forceinline__ short f2b(float f) {
  union { float f; unsigned u; } x; x.f = f;
  unsigned r = x.u + 0x7FFFu + ((x.u >> 16) & 1u);  // RNE
  return (short)(r >> 16);
}

struct WPtrs { const float* w[10]; };

struct NodeSet {
  const unsigned short* X16[4];
  const float* Xf[4];
  const short* Wt[4];
  const float* bias[4];
  unsigned short* o16[4];
  float* of[4];
};
struct EdgeSet {
  const int* ei; const float* tvec; const float* lu; const float* msg;
  const short* WeT; const int* pos; unsigned short* e16g;
};

// ---------------- device bodies (round-13/14 proven) ----------------
__device__ __forceinline__ void node_block(char* smem, int tid, int nb,
                                           const NodeSet& N, int use16) {
  short* As = (short*)smem;
  const int l = tid & 63;
  const int w = tid >> 6;
  const int colb = l & 15;
  const int g = l >> 4;
  const int job = nb / 782;
  const int m0 = (nb - job * 782) * 64;
  const bool fullblk = (m0 + 64 <= N_NODES);
  const short* Wt = N.Wt[job];
  const float* bias = N.bias[job];
  unsigned short* o16 = N.o16[job];
  float* of = N.of[job];

  if (use16) {
    const unsigned short* X = N.X16[job];
    if (fullblk) {
#pragma unroll
      for (int i = 0; i < 4; ++i) {
        int flat = tid + i * 512;
        int r = flat >> 5, cg = flat & 31;
        *(s16x8*)&As[r * 264 + cg * 8] = *(const s16x8*)(X + (size_t)(m0 + r) * 256 + cg * 8);
      }
    } else {
#pragma unroll
      for (int i = 0; i < 4; ++i) {
        int flat = tid + i * 512;
        int r = flat >> 5, cg = flat & 31;
        s16x8 v = (s16x8)(short)0;
        if (m0 + r < N_NODES) v = *(const s16x8*)(X + (size_t)(m0 + r) * 256 + cg * 8);
        *(s16x8*)&As[r * 264 + cg * 8] = v;
      }
    }
  } else {
    const float* X = N.Xf[job];
#pragma unroll
    for (int i = 0; i < 8; ++i) {
      int flat = tid + i * 512;
      int r = flat >> 6, c4 = flat & 63;
      float4 xv = make_float4(0.f, 0.f, 0.f, 0.f);
      if (fullblk || m0 + r < N_NODES) xv = *(const float4*)(X + (size_t)(m0 + r) * 256 + c4 * 4);
      s16x4 sv; sv[0] = f2b(xv.x); sv[1] = f2b(xv.y); sv[2] = f2b(xv.z); sv[3] = f2b(xv.w);
      *(s16x4*)&As[r * 264 + c4 * 4] = sv;
    }
  }
  __syncthreads();

  const short* wbase0 = Wt + (((2 * w + 0) * 8) * 16 + colb) * 32 + g * 8;
  const short* wbase1 = Wt + (((2 * w + 1) * 8) * 16 + colb) * 32 + g * 8;

  f32x4 acc[4][2];
#pragma unroll
  for (int m = 0; m < 4; ++m) { acc[m][0] = (f32x4)(0.0f); acc[m][1] = (f32x4)(0.0f); }
#pragma unroll
  for (int ks = 0; ks < 8; ++ks) {
    s16x8 b0 = *(const s16x8*)(wbase0 + ks * 512);
    s16x8 b1 = *(const s16x8*)(wbase1 + ks * 512);
#pragma unroll
    for (int m = 0; m < 4; ++m) {
      s16x8 a = *(const s16x8*)&As[(16 * m + colb) * 264 + ks * 32 + g * 8];
      acc[m][0] = __builtin_amdgcn_mfma_f32_16x16x32_bf16(a, b0, acc[m][0], 0, 0, 0);
      acc[m][1] = __builtin_amdgcn_mfma_f32_16x16x32_bf16(a, b1, acc[m][1], 0, 0, 0);
    }
  }
  __syncthreads();   // done with As data

  if (of) {          // f32 output: bounce 32 rows at a time
    float* buf = (float*)smem;
#pragma unroll 1
    for (int half = 0; half < 2; ++half) {
#pragma unroll
      for (int j = 0; j < 2; ++j) {
        int col = (2 * w + j) * 16 + colb;
        float bv = bias[col];
#pragma unroll
        for (int mm = 0; mm < 2; ++mm) {
          int m = half * 2 + mm;
#pragma unroll
          for (int r = 0; r < 4; ++r)
            buf[(16 * mm + g * 4 + r) * 260 + col] = acc[m][j][r] + bv;
        }
      }
      __syncthreads();
#pragma unroll
      for (int i = 0; i < 4; ++i) {
        int flat = tid + i * 512;
        int row = flat >> 6, ch = flat & 63;
        int grow = m0 + half * 32 + row;
        if (fullblk || grow < N_NODES)
          *(float4*)(of + (size_t)grow * 256 + ch * 4) = *(const float4*)&buf[row * 260 + ch * 4];
      }
      __syncthreads();
    }
  } else {           // bf16 output: full 64-row bounce
    short* buf = (short*)smem;
#pragma unroll
    for (int j = 0; j < 2; ++j) {
      int col = (2 * w + j) * 16 + colb;
      float bv = bias[col];
#pragma unroll
      for (int m = 0; m < 4; ++m)
#pragma unroll
        for (int r = 0; r < 4; ++r)
          buf[(16 * m + g * 4 + r) * 264 + col] = f2b(acc[m][j][r] + bv);
    }
    __syncthreads();
#pragma unroll
    for (int i = 0; i < 4; ++i) {
      int flat = tid + i * 512;
      int row = flat >> 5, ch = flat & 31;
      if (fullblk || m0 + row < N_NODES)
        *(s16x8*)(o16 + (size_t)(m0 + row) * 256 + ch * 8) = *(const s16x8*)&buf[row * 264 + ch * 8];
    }
  }
}

__device__ __forceinline__ void edge_block(char* smem, int tid, int eb,
                                           const EdgeSet& E,
                                           const float* Wtim, const float* btim) {
  short* attr = (short*)smem;                       // 64*264 bf16 = 33792 B
  float* rel  = (float*)(smem + 33792);             // 256 B
  int*   poss = (int*)(smem + 34048);               // 256 B
  const int l = tid & 63;
  const int w = tid >> 6;
  const int colb = l & 15;
  const int g = l >> 4;
  const int e0 = eb * 64;

  const float wt = Wtim[tid & 127], bt = btim[tid & 127];

  if (tid < 64) {
    rel[tid] = E.tvec[e0 + tid] - E.lu[E.ei[e0 + tid]];
    poss[tid] = E.pos[e0 + tid];
  }
#pragma unroll
  for (int i = 0; i < 4; ++i) {
    int flat = tid + i * 512;
    int row = flat >> 5, c4 = flat & 31;
    float4 mv = *(const float4*)(E.msg + (size_t)(e0 + row) * 128 + c4 * 4);
    s16x4 sv; sv[0] = f2b(mv.x); sv[1] = f2b(mv.y); sv[2] = f2b(mv.z); sv[3] = f2b(mv.w);
    *(s16x4*)&attr[row * 264 + 128 + c4 * 4] = sv;
  }
  __syncthreads();   // rel + msg staged

  { // time-encoder cols
    int col = tid & 127;
    int r0 = (tid >> 7) * 16;
#pragma unroll
    for (int i = 0; i < 16; ++i)
      attr[(r0 + i) * 264 + col] = f2b(__cosf(rel[r0 + i] * wt + bt));
  }
  __syncthreads();

  const short* wbase0 = E.WeT + (((2 * w + 0) * 8) * 16 + colb) * 32 + g * 8;
  const short* wbase1 = E.WeT + (((2 * w + 1) * 8) * 16 + colb) * 32 + g * 8;
  f32x4 acc[4][2];
#pragma unroll
  for (int m = 0; m < 4; ++m) { acc[m][0] = (f32x4)(0.0f); acc[m][1] = (f32x4)(0.0f); }
#pragma unroll
  for (int ks = 0; ks < 8; ++ks) {
    s16x8 b0 = *(const s16x8*)(wbase0 + ks * 512);
    s16x8 b1 = *(const s16x8*)(wbase1 + ks * 512);
#pragma unroll
    for (int m = 0; m < 4; ++m) {
      s16x8 a = *(const s16x8*)&attr[(16 * m + colb) * 264 + ks * 32 + g * 8];
      acc[m][0] = __builtin_amdgcn_mfma_f32_16x16x32_bf16(a, b0, acc[m][0], 0, 0, 0);
      acc[m][1] = __builtin_amdgcn_mfma_f32_16x16x32_bf16(a, b1, acc[m][1], 0, 0, 0);
    }
  }
  __syncthreads();   // all waves done reading attr
#pragma unroll
  for (int j = 0; j < 2; ++j)
#pragma unroll
    for (int m = 0; m < 4; ++m)
#pragma unroll
      for (int r = 0; r < 4; ++r)
        attr[(16 * m + g * 4 + r) * 264 + (2 * w + j) * 16 + colb] = f2b(acc[m][j][r]);
  __syncthreads();

#pragma unroll
  for (int i = 0; i < 4; ++i) {
    int flat = tid + i * 512;
    int row = flat >> 5, cg = flat & 31;
    size_t slot = (size_t)poss[row];
    *(s16x8*)(E.e16g + slot * 256 + cg * 8) = *(const s16x8*)&attr[row * 264 + cg * 8];
  }
}

// per-dst aggregate body (proven, 4-way ILP)
__device__ __forceinline__ void process_dst(
    int d, int c0, const int* __restrict__ start, const unsigned short* __restrict__ esrc,
    const unsigned short* __restrict__ Q16, const unsigned short* __restrict__ K16,
    const unsigned short* __restrict__ V16, const unsigned short* __restrict__ e16,
    float* __restrict__ out)
{
  const int s0 = start[d], s1 = start[d + 1];
  if (s1 <= s0) return;

  s16x4 qv = *(const s16x4*)(Q16 + (size_t)d * 256 + c0);
  const float q0 = b2f((unsigned short)qv[0]), q1 = b2f((unsigned short)qv[1]);
  const float q2 = b2f((unsigned short)qv[2]), q3 = b2f((unsigned short)qv[3]);

  float den = 0.f;
  float a0 = 0.f, a1 = 0.f, a2 = 0.f, a3 = 0.f;
  int p = s0;

#define EDGE_LOAD(J, PP)                                                    \
    int s##J = (int)esrc[PP];                                               \
    s16x4 ev##J = *(const s16x4*)(e16 + (size_t)(PP) * 256 + c0);           \
    s16x4 kv##J = *(const s16x4*)(K16 + (size_t)s##J * 256 + c0);           \
    s16x4 vv##J = *(const s16x4*)(V16 + (size_t)s##J * 256 + c0);           \
    float e0##J = b2f((unsigned short)ev##J[0]), e1##J = b2f((unsigned short)ev##J[1]); \
    float e2##J = b2f((unsigned short)ev##J[2]), e3##J = b2f((unsigned short)ev##J[3]); \
    float dt##J = q0 * (b2f((unsigned short)kv##J[0]) + e0##J)              \
                + q1 * (b2f((unsigned short)kv##J[1]) + e1##J)              \
                + q2 * (b2f((unsigned short)kv##J[2]) + e2##J)              \
                + q3 * (b2f((unsigned short)kv##J[3]) + e3##J);

#define EDGE_ACC(J)                                                         \
    den += ex##J;                                                           \
    a0 += ex##J * (b2f((unsigned short)vv##J[0]) + e0##J);                  \
    a1 += ex##J * (b2f((unsigned short)vv##J[1]) + e1##J);                  \
    a2 += ex##J * (b2f((unsigned short)vv##J[2]) + e2##J);                  \
    a3 += ex##J * (b2f((unsigned short)vv##J[3]) + e3##J);

  for (; p + 4 <= s1; p += 4) {
    EDGE_LOAD(A, p)  EDGE_LOAD(B, p + 1)  EDGE_LOAD(C, p + 2)  EDGE_LOAD(D, p + 3)
    dtA += __shfl_xor(dtA, 1);  dtB += __shfl_xor(dtB, 1);
    dtC += __shfl_xor(dtC, 1);  dtD += __shfl_xor(dtD, 1);
    dtA += __shfl_xor(dtA, 2);  dtB += __shfl_xor(dtB, 2);
    dtC += __shfl_xor(dtC, 2);  dtD += __shfl_xor(dtD, 2);
    dtA += __shfl_xor(dtA, 4);  dtB += __shfl_xor(dtB, 4);
    dtC += __shfl_xor(dtC, 4);  dtD += __shfl_xor(dtD, 4);
    dtA += __shfl_xor(dtA, 8);  dtB += __shfl_xor(dtB, 8);
    dtC += __shfl_xor(dtC, 8);  dtD += __shfl_xor(dtD, 8);
    dtA += __shfl_xor(dtA, 16); dtB += __shfl_xor(dtB, 16);
    dtC += __shfl_xor(dtC, 16); dtD += __shfl_xor(dtD, 16);
    float exA = __expf(dtA * INV_SQRT_C), exB = __expf(dtB * INV_SQRT_C);
    float exC = __expf(dtC * INV_SQRT_C), exD = __expf(dtD * INV_SQRT_C);
    EDGE_ACC(A) EDGE_ACC(B) EDGE_ACC(C) EDGE_ACC(D)
  }
  for (; p < s1; ++p) {
    EDGE_LOAD(T, p)
    dtT += __shfl_xor(dtT, 1);
    dtT += __shfl_xor(dtT, 2);
    dtT += __shfl_xor(dtT, 4);
    dtT += __shfl_xor(dtT, 8);
    dtT += __shfl_xor(dtT, 16);
    float exT = __expf(dtT * INV_SQRT_C);
    EDGE_ACC(T)
  }
#undef EDGE_LOAD
#undef EDGE_ACC

  float inv = 1.f / (den + 1e-16f);
  float4* op = (float4*)(out + (size_t)d * 256 + c0);
  float4 o = *op;
  o.x += a0 * inv; o.y += a1 * inv; o.z += a2 * inv; o.w += a3 * inv;
  *op = o;
}

// ---------------- setup: prep_transpose + conv_x + csr_count fused ----------
__global__ __launch_bounds__(256) void setup_fused(
    WPtrs p, short* __restrict__ WtT,
    const float* __restrict__ xu, const float* __restrict__ xi,
    unsigned short* __restrict__ x16u, unsigned short* __restrict__ x16i, int nconv,
    const int* __restrict__ eia, const int* __restrict__ eib, int* __restrict__ counts)
{
  __shared__ short T[256 * 66];
  const int bx = blockIdx.x;
  const int tid = threadIdx.x;

  if (bx < NB_PREP) {
    const int wi = bx >> 2, cq = bx & 3;
    const float* w = p.w[wi];
    short* o = WtT + wi * 65536;
#pragma unroll
    for (int i = 0; i < 64; ++i) {
      int flat = tid + i * 256;
      int k = flat >> 6, cc = flat & 63;
      T[k * 66 + cc] = f2b(w[k * 256 + cq * 64 + cc]);
    }
    __syncthreads();
#pragma unroll
    for (int i = 0; i < 8; ++i) {
      int flat2 = tid + i * 256;
      int g = flat2 & 3, colb = (flat2 >> 2) & 15, ks = (flat2 >> 6) & 7, ctl = flat2 >> 9;
      int ct = cq * 4 + ctl;
      s16x8 v;
#pragma unroll
      for (int j = 0; j < 8; ++j)
        v[j] = T[(ks * 32 + g * 8 + j) * 66 + ctl * 16 + colb];
      *(s16x8*)(o + (((ct * 8 + ks) * 16 + colb) * 32 + g * 8)) = v;
    }
    return;
  }
  int cb = bx - NB_PREP;
  if (cb < nconv) {                    // conv_x
    int y = cb >= (nconv / 2);
    int xb = y ? cb - nconv / 2 : cb;
    const float* in = y ? xi : xu;
    unsigned short* out = y ? x16i : x16u;
    size_t base = ((size_t)xb * 256 + tid) * 8;
    float4 a = *(const float4*)(in + base);
    float4 b = *(const float4*)(in + base + 4);
    s16x8 v;
    v[0] = f2b(a.x); v[1] = f2b(a.y); v[2] = f2b(a.z); v[3] = f2b(a.w);
    v[4] = f2b(b.x); v[5] = f2b(b.y); v[6] = f2b(b.z); v[7] = f2b(b.w);
    *(s16x8*)(out + base) = v;
    return;
  }
  cb -= nconv;                         // csr_count
  int y = cb >= (NB_CNT / 2);
  int tb = y ? cb - NB_CNT / 2 : cb;
  const int* ei = y ? eib : eia;
  int* c = counts + y * N_NODES;
  int t = tb * 256 + tid;
  if (t < E_EDGES) atomicAdd(&c[ei[E_EDGES + t]], 1);
}

// ---------------- CSR scan / fill ----------------
__global__ __launch_bounds__(1024) void csr_scan2(int* __restrict__ counts,
                                                  int* __restrict__ start) {
  int* cnt = counts + blockIdx.x * N_NODES;
  int* st  = start + blockIdx.x * (N_NODES + 1);
  __shared__ int wsum[16];
  __shared__ int chunk_tot;
  __shared__ int carry_s;
  const int tid = threadIdx.x, lane = tid & 63, wid = tid >> 6;
  if (tid == 0) carry_s = 0;
  __syncthreads();
  for (int base = 0; base < N_NODES; base += 1024) {
    int gi = base + tid;
    int x = (gi < N_NODES) ? cnt[gi] : 0;
    int v = x;
#pragma unroll
    for (int d = 1; d < 64; d <<= 1) {
      int t = __shfl_up(v, d);
      if (lane >= d) v += t;
    }
    if (lane == 63) wsum[wid] = v;
    __syncthreads();
    if (tid == 0) {
      int run = 0;
#pragma unroll
      for (int i = 0; i < 16; ++i) { int t = wsum[i]; wsum[i] = run; run += t; }
      chunk_tot = run;
    }
    __syncthreads();
    if (gi < N_NODES) {
      int excl = carry_s + wsum[wid] + v - x;
      st[gi] = excl;
      cnt[gi] = excl;       // becomes the fill cursor
    }
    __syncthreads();
    if (tid == 0) carry_s += chunk_tot;
  }
  if (tid == 0) st[N_NODES] = carry_s;
}

__global__ __launch_bounds__(256) void csr_fill2(const int* __restrict__ eia,
                                                 const int* __restrict__ eib,
                                                 int* __restrict__ counts,
                                                 int* __restrict__ pos,
                                                 unsigned short* __restrict__ esrc) {
  int t = blockIdx.x * 256 + threadIdx.x;
  const int* ei = blockIdx.y ? eib : eia;
  int* cur = counts + blockIdx.y * N_NODES;
  int* ps  = pos + blockIdx.y * E_EDGES;
  unsigned short* es = esrc + (size_t)blockIdx.y * E_EDGES;
  if (t < E_EDGES) {
    int d = ei[E_EDGES + t];
    int p = atomicAdd(&cur[d], 1);
    ps[t] = p;
    es[p] = (unsigned short)ei[t];
  }
}

// ---------------- fused node+edge: single type ----------------
struct FusedArgs { NodeSet n; EdgeSet e; const float* Wtim; const float* btim; int use16; };

__global__ __launch_bounds__(512) void fused_ne(FusedArgs A) {
  __shared__ __align__(16) char smem[34816];
  const int bx = blockIdx.x;
  int nb = -1, eb = -1;
  if (bx < NB_PAIR) { if (bx & 1) eb = bx >> 1; else nb = bx >> 1; }
  else nb = NB_EDGE + (bx - NB_PAIR);
  if (nb >= 0) node_block(smem, threadIdx.x, nb, A.n, A.use16);
  else         edge_block(smem, threadIdx.x, eb, A.e, A.Wtim, A.btim);
}

// ---------------- standalone aggregate (persistent waves, max TLP) ----------
__global__ __launch_bounds__(256) void aggregate_fused5(
    const int* __restrict__ start, const unsigned short* __restrict__ esrc,
    const unsigned short* __restrict__ Q16, const unsigned short* __restrict__ K16,
    const unsigned short* __restrict__ V16, const unsigned short* __restrict__ e16,
    float* __restrict__ out)
{
  const int wave = blockIdx.x * 4 + (threadIdx.x >> 6);
  const int nwaves = gridDim.x * 4;
  const int c0 = (threadIdx.x & 63) * 4;
  for (int d = wave; d < N_NODES; d += nwaves)
    process_dst(d, c0, start, esrc, Q16, K16, V16, e16, out);
}

extern "C" void kernel_launch(void* const* d_in, const int* in_sizes, int n_in,
                              void* d_out, int out_size, void* d_ws, size_t ws_size,
                              hipStream_t stream) {
  const float* x_user  = (const float*)d_in[0];
  const float* x_item  = (const float*)d_in[1];
  const float* lu_user = (const float*)d_in[2];
  const float* lu_item = (const float*)d_in[3];
  const int*   ei_a    = (const int*)d_in[4];
  const int*   ei_b    = (const int*)d_in[5];
  const float* t_a     = (const float*)d_in[6];
  const float* t_b     = (const float*)d_in[7];
  const float* msg_a   = (const float*)d_in[8];
  const float* msg_b   = (const float*)d_in[9];
  const float* W_t     = (const float*)d_in[10];
  const float* b_t     = (const float*)d_in[11];
  const float* Wq_a = (const float*)d_in[12]; const float* bq_a = (const float*)d_in[13];
  const float* Wk_a = (const float*)d_in[14]; const float* bk_a = (const float*)d_in[15];
  const float* Wv_a = (const float*)d_in[16]; const float* bv_a = (const float*)d_in[17];
  const float* We_a = (const float*)d_in[18];
  const float* Ws_a = (const float*)d_in[19]; const float* bs_a = (const float*)d_in[20];
  const float* Wq_b = (const float*)d_in[21]; const float* bq_b = (const float*)d_in[22];
  const float* Wk_b = (const float*)d_in[23]; const float* bk_b = (const float*)d_in[24];
  const float* Wv_b = (const float*)d_in[25]; const float* bv_b = (const float*)d_in[26];
  const float* We_b = (const float*)d_in[27];
  const float* Ws_b = (const float*)d_in[28]; const float* bs_b = (const float*)d_in[29];

  float* out_user = (float*)d_out;
  float* out_item = (float*)d_out + (size_t)N_NODES * 256;

  WPtrs wp;
  wp.w[0] = Wq_a; wp.w[1] = Wk_a; wp.w[2] = Wv_a; wp.w[3] = Ws_a; wp.w[4] = We_a;
  wp.w[5] = Wq_b; wp.w[6] = Wk_b; wp.w[7] = Wv_b; wp.w[8] = Ws_b; wp.w[9] = We_b;

  dim3 blk(256);
  dim3 blk512(512);
  dim3 gEt2((E_EDGES + 255) / 256, 2);

  // ws layout
  char* ws = (char*)d_ws;
  size_t off = 0;
  short* WtT = (short*)(ws + off); off += (size_t)10 * 65536 * 2;
  unsigned short* Q16 = (unsigned short*)(ws + off); off += (size_t)N_NODES * 256 * 2;
  unsigned short* K16 = (unsigned short*)(ws + off); off += (size_t)N_NODES * 256 * 2;
  unsigned short* V16 = (unsigned short*)(ws + off); off += (size_t)N_NODES * 256 * 2;
  unsigned short* e16 = (unsigned short*)(ws + off); off += (size_t)E_EDGES * 256 * 2;
  int* pos    = (int*)(ws + off); off += (size_t)2 * E_EDGES * 4;
  int* counts = (int*)(ws + off); off += (size_t)2 * N_NODES * 4;
  int* startb = (int*)(ws + off); off += (size_t)2 * (N_NODES + 1) * 4;
  unsigned short* esrc = (unsigned short*)(ws + off); off += (size_t)2 * E_EDGES * 2;
  const size_t off_base = off;
  unsigned short* X16u = (unsigned short*)(ws + off); off += (size_t)N_NODES * 256 * 2;
  unsigned short* X16i = (unsigned short*)(ws + off); off += (size_t)N_NODES * 256 * 2;
  const size_t off_t1 = off;
  const bool use_x16 = (ws_size >= off_t1);
  if (!use_x16 && ws_size < off_base) return;   // fail loudly

  const int nconv = use_x16 ? NB_CONV : 0;

  hipMemsetAsync(counts, 0, (size_t)2 * N_NODES * 4, stream);
  setup_fused<<<dim3(NB_PREP + nconv + NB_CNT), blk, 0, stream>>>(
      wp, WtT, x_user, x_item, X16u, X16i, nconv, ei_a, ei_b, counts);
  csr_scan2<<<2, 1024, 0, stream>>>(counts, startb);
  csr_fill2<<<gEt2, blk, 0, stream>>>(ei_a, ei_b, counts, pos, esrc);

  // Build per-type sets
  NodeSet na, nb_;
  na.X16[0] = X16u; na.X16[1] = X16u; na.X16[2] = X16i; na.X16[3] = X16i;
  na.Xf[0] = x_user; na.Xf[1] = x_user; na.Xf[2] = x_item; na.Xf[3] = x_item;
  na.Wt[0] = WtT + 1 * 65536; na.Wt[1] = WtT + 2 * 65536;
  na.Wt[2] = WtT + 0 * 65536; na.Wt[3] = WtT + 3 * 65536;
  na.bias[0] = bk_a; na.bias[1] = bv_a; na.bias[2] = bq_a; na.bias[3] = bs_a;
  na.o16[0] = K16; na.o16[1] = V16; na.o16[2] = Q16; na.o16[3] = nullptr;
  na.of[0] = nullptr; na.of[1] = nullptr; na.of[2] = nullptr; na.of[3] = out_item;

  nb_.X16[0] = X16i; nb_.X16[1] = X16i; nb_.X16[2] = X16u; nb_.X16[3] = X16u;
  nb_.Xf[0] = x_item; nb_.Xf[1] = x_item; nb_.Xf[2] = x_user; nb_.Xf[3] = x_user;
  nb_.Wt[0] = WtT + 6 * 65536; nb_.Wt[1] = WtT + 7 * 65536;
  nb_.Wt[2] = WtT + 5 * 65536; nb_.Wt[3] = WtT + 8 * 65536;
  nb_.bias[0] = bk_b; nb_.bias[1] = bv_b; nb_.bias[2] = bq_b; nb_.bias[3] = bs_b;
  nb_.o16[0] = K16; nb_.o16[1] = V16; nb_.o16[2] = Q16; nb_.o16[3] = nullptr;
  nb_.of[0] = nullptr; nb_.of[1] = nullptr; nb_.of[2] = nullptr; nb_.of[3] = out_user;

  EdgeSet ea, eb_;
  ea.ei = ei_a; ea.tvec = t_a; ea.lu = lu_user; ea.msg = msg_a;
  ea.WeT = WtT + 4 * 65536; ea.pos = pos; ea.e16g = e16;
  eb_.ei = ei_b; eb_.tvec = t_b; eb_.lu = lu_item; eb_.msg = msg_b;
  eb_.WeT = WtT + 9 * 65536; eb_.pos = pos + E_EDGES; eb_.e16g = e16;

  const int u16 = use_x16 ? 1 : 0;

  // ---- type a: fused node+edge, then aggregate ----
  FusedArgs Aa; Aa.n = na; Aa.e = ea; Aa.Wtim = W_t; Aa.btim = b_t; Aa.use16 = u16;
  fused_ne<<<dim3(NB_FUSED), blk512, 0, stream>>>(Aa);
  aggregate_fused5<<<dim3(2048), blk, 0, stream>>>(startb, esrc, Q16, K16, V16, e16, out_item);

  // ---- type b ----
  FusedArgs Ab; Ab.n = nb_; Ab.e = eb_; Ab.Wtim = W_t; Ab.btim = b_t; Ab.use16 = u16;
  fused_ne<<<dim3(NB_FUSED), blk512, 0, stream>>>(Ab);
  aggregate_fused5<<<dim3(2048), blk, 0, stream>>>(startb + (N_NODES + 1), esrc + E_EDGES,
      Q16, K16, V16, e16, out_user);
}

// Round 17
// 510.068 us; speedup vs baseline: 1.2144x; 1.1194x over previous
//
#include <hip/hip_runtime.h>
#include <hip/hip_bf16.h>

#define N_NODES 50000
#define E_EDGES 200000
static constexpr float INV_SQRT_C = 0.08838834764831845f; // 1/sqrt(128)
static constexpr int NB_NODE = ((N_NODES + 63) / 64) * 4;  // 3128
static constexpr int NB_EDGE = E_EDGES / 64;               // 3125
static constexpr int NB_PAIR = 2 * NB_EDGE;                // 6250 interleaved
static constexpr int NB_FUSED = NB_NODE + NB_EDGE;         // 6253
static constexpr int NB_PREP = 40;
static constexpr int NB_CONV = 12500;
static constexpr int NB_CNT  = ((E_EDGES + 255) / 256) * 2; // 1564

typedef __attribute__((ext_vector_type(4))) float f32x4;
typedef __attribute__((ext_vector_type(8))) short s16x8;
typedef __attribute__((ext_vector_type(4))) short s16x4;

__device__ __forceinline__ float b2f(unsigned short u) {
  union { unsigned u; float f; } x; x.u = ((unsigned)u) << 16; return x.f;
}
__device__ __forceinline__ short f2b(float f) {
  union { float f; unsigned u; } x; x.f = f;
  unsigned r = x.u + 0x7FFFu + ((x.u >> 16) & 1u);  // RNE
  return (short)(r >> 16);
}

struct WPtrs { const float* w[10]; };

struct NodeSet {
  const unsigned short* X16[4];
  const float* Xf[4];
  const short* Wt[4];
  const float* bias[4];
  unsigned short* o16[4];
  float* of[4];
};
struct EdgeSet {
  const int* ei; const float* tvec; const float* lu; const float* msg;
  const short* WeT; const int* pos; unsigned short* e16g;
};

// ---------------- device bodies (round-16 proven) ----------------
__device__ __forceinline__ void node_block(char* smem, int tid, int nb,
                                           const NodeSet& N, int use16) {
  short* As = (short*)smem;
  const int l = tid & 63;
  const int w = tid >> 6;
  const int colb = l & 15;
  const int g = l >> 4;
  const int job = nb / 782;
  const int m0 = (nb - job * 782) * 64;
  const bool fullblk = (m0 + 64 <= N_NODES);
  const short* Wt = N.Wt[job];
  const float* bias = N.bias[job];
  unsigned short* o16 = N.o16[job];
  float* of = N.of[job];

  if (use16) {
    const unsigned short* X = N.X16[job];
    if (fullblk) {
#pragma unroll
      for (int i = 0; i < 4; ++i) {
        int flat = tid + i * 512;
        int r = flat >> 5, cg = flat & 31;
        *(s16x8*)&As[r * 264 + cg * 8] = *(const s16x8*)(X + (size_t)(m0 + r) * 256 + cg * 8);
      }
    } else {
#pragma unroll
      for (int i = 0; i < 4; ++i) {
        int flat = tid + i * 512;
        int r = flat >> 5, cg = flat & 31;
        s16x8 v = (s16x8)(short)0;
        if (m0 + r < N_NODES) v = *(const s16x8*)(X + (size_t)(m0 + r) * 256 + cg * 8);
        *(s16x8*)&As[r * 264 + cg * 8] = v;
      }
    }
  } else {
    const float* X = N.Xf[job];
#pragma unroll
    for (int i = 0; i < 8; ++i) {
      int flat = tid + i * 512;
      int r = flat >> 6, c4 = flat & 63;
      float4 xv = make_float4(0.f, 0.f, 0.f, 0.f);
      if (fullblk || m0 + r < N_NODES) xv = *(const float4*)(X + (size_t)(m0 + r) * 256 + c4 * 4);
      s16x4 sv; sv[0] = f2b(xv.x); sv[1] = f2b(xv.y); sv[2] = f2b(xv.z); sv[3] = f2b(xv.w);
      *(s16x4*)&As[r * 264 + c4 * 4] = sv;
    }
  }
  __syncthreads();

  const short* wbase0 = Wt + (((2 * w + 0) * 8) * 16 + colb) * 32 + g * 8;
  const short* wbase1 = Wt + (((2 * w + 1) * 8) * 16 + colb) * 32 + g * 8;

  f32x4 acc[4][2];
#pragma unroll
  for (int m = 0; m < 4; ++m) { acc[m][0] = (f32x4)(0.0f); acc[m][1] = (f32x4)(0.0f); }
#pragma unroll
  for (int ks = 0; ks < 8; ++ks) {
    s16x8 b0 = *(const s16x8*)(wbase0 + ks * 512);
    s16x8 b1 = *(const s16x8*)(wbase1 + ks * 512);
#pragma unroll
    for (int m = 0; m < 4; ++m) {
      s16x8 a = *(const s16x8*)&As[(16 * m + colb) * 264 + ks * 32 + g * 8];
      acc[m][0] = __builtin_amdgcn_mfma_f32_16x16x32_bf16(a, b0, acc[m][0], 0, 0, 0);
      acc[m][1] = __builtin_amdgcn_mfma_f32_16x16x32_bf16(a, b1, acc[m][1], 0, 0, 0);
    }
  }
  __syncthreads();   // done with As data

  if (of) {          // f32 output: bounce 32 rows at a time
    float* buf = (float*)smem;
#pragma unroll 1
    for (int half = 0; half < 2; ++half) {
#pragma unroll
      for (int j = 0; j < 2; ++j) {
        int col = (2 * w + j) * 16 + colb;
        float bv = bias[col];
#pragma unroll
        for (int mm = 0; mm < 2; ++mm) {
          int m = half * 2 + mm;
#pragma unroll
          for (int r = 0; r < 4; ++r)
            buf[(16 * mm + g * 4 + r) * 260 + col] = acc[m][j][r] + bv;
        }
      }
      __syncthreads();
#pragma unroll
      for (int i = 0; i < 4; ++i) {
        int flat = tid + i * 512;
        int row = flat >> 6, ch = flat & 63;
        int grow = m0 + half * 32 + row;
        if (fullblk || grow < N_NODES)
          *(float4*)(of + (size_t)grow * 256 + ch * 4) = *(const float4*)&buf[row * 260 + ch * 4];
      }
      __syncthreads();
    }
  } else {           // bf16 output: full 64-row bounce
    short* buf = (short*)smem;
#pragma unroll
    for (int j = 0; j < 2; ++j) {
      int col = (2 * w + j) * 16 + colb;
      float bv = bias[col];
#pragma unroll
      for (int m = 0; m < 4; ++m)
#pragma unroll
        for (int r = 0; r < 4; ++r)
          buf[(16 * m + g * 4 + r) * 264 + col] = f2b(acc[m][j][r] + bv);
    }
    __syncthreads();
#pragma unroll
    for (int i = 0; i < 4; ++i) {
      int flat = tid + i * 512;
      int row = flat >> 5, ch = flat & 31;
      if (fullblk || m0 + row < N_NODES)
        *(s16x8*)(o16 + (size_t)(m0 + row) * 256 + ch * 8) = *(const s16x8*)&buf[row * 264 + ch * 8];
    }
  }
}

__device__ __forceinline__ void edge_block(char* smem, int tid, int eb,
                                           const EdgeSet& E,
                                           const float* Wtim, const float* btim) {
  short* attr = (short*)smem;                       // 64*264 bf16 = 33792 B
  float* rel  = (float*)(smem + 33792);             // 256 B
  int*   poss = (int*)(smem + 34048);               // 256 B
  const int l = tid & 63;
  const int w = tid >> 6;
  const int colb = l & 15;
  const int g = l >> 4;
  const int e0 = eb * 64;

  const float wt = Wtim[tid & 127], bt = btim[tid & 127];

  if (tid < 64) {
    rel[tid] = E.tvec[e0 + tid] - E.lu[E.ei[e0 + tid]];
    poss[tid] = E.pos[e0 + tid];
  }
#pragma unroll
  for (int i = 0; i < 4; ++i) {
    int flat = tid + i * 512;
    int row = flat >> 5, c4 = flat & 31;
    float4 mv = *(const float4*)(E.msg + (size_t)(e0 + row) * 128 + c4 * 4);
    s16x4 sv; sv[0] = f2b(mv.x); sv[1] = f2b(mv.y); sv[2] = f2b(mv.z); sv[3] = f2b(mv.w);
    *(s16x4*)&attr[row * 264 + 128 + c4 * 4] = sv;
  }
  __syncthreads();   // rel + msg staged

  { // time-encoder cols
    int col = tid & 127;
    int r0 = (tid >> 7) * 16;
#pragma unroll
    for (int i = 0; i < 16; ++i)
      attr[(r0 + i) * 264 + col] = f2b(__cosf(rel[r0 + i] * wt + bt));
  }
  __syncthreads();

  const short* wbase0 = E.WeT + (((2 * w + 0) * 8) * 16 + colb) * 32 + g * 8;
  const short* wbase1 = E.WeT + (((2 * w + 1) * 8) * 16 + colb) * 32 + g * 8;
  f32x4 acc[4][2];
#pragma unroll
  for (int m = 0; m < 4; ++m) { acc[m][0] = (f32x4)(0.0f); acc[m][1] = (f32x4)(0.0f); }
#pragma unroll
  for (int ks = 0; ks < 8; ++ks) {
    s16x8 b0 = *(const s16x8*)(wbase0 + ks * 512);
    s16x8 b1 = *(const s16x8*)(wbase1 + ks * 512);
#pragma unroll
    for (int m = 0; m < 4; ++m) {
      s16x8 a = *(const s16x8*)&attr[(16 * m + colb) * 264 + ks * 32 + g * 8];
      acc[m][0] = __builtin_amdgcn_mfma_f32_16x16x32_bf16(a, b0, acc[m][0], 0, 0, 0);
      acc[m][1] = __builtin_amdgcn_mfma_f32_16x16x32_bf16(a, b1, acc[m][1], 0, 0, 0);
    }
  }
  __syncthreads();   // all waves done reading attr
#pragma unroll
  for (int j = 0; j < 2; ++j)
#pragma unroll
    for (int m = 0; m < 4; ++m)
#pragma unroll
      for (int r = 0; r < 4; ++r)
        attr[(16 * m + g * 4 + r) * 264 + (2 * w + j) * 16 + colb] = f2b(acc[m][j][r]);
  __syncthreads();

#pragma unroll
  for (int i = 0; i < 4; ++i) {
    int flat = tid + i * 512;
    int row = flat >> 5, cg = flat & 31;
    size_t slot = (size_t)poss[row];
    *(s16x8*)(E.e16g + slot * 256 + cg * 8) = *(const s16x8*)&attr[row * 264 + cg * 8];
  }
}

// ---------------- aggregate bodies ----------------
#define EDGE_LOAD(J, PP)                                                    \
    int s##J = (int)esrc[PP];                                               \
    s16x4 ev##J = *(const s16x4*)(e16 + (size_t)(PP) * 256 + c0);           \
    s16x4 kv##J = *(const s16x4*)(K16 + (size_t)s##J * 256 + c0);           \
    s16x4 vv##J = *(const s16x4*)(V16 + (size_t)s##J * 256 + c0);           \
    float e0##J = b2f((unsigned short)ev##J[0]), e1##J = b2f((unsigned short)ev##J[1]); \
    float e2##J = b2f((unsigned short)ev##J[2]), e3##J = b2f((unsigned short)ev##J[3]); \
    float dt##J = q0 * (b2f((unsigned short)kv##J[0]) + e0##J)              \
                + q1 * (b2f((unsigned short)kv##J[1]) + e1##J)              \
                + q2 * (b2f((unsigned short)kv##J[2]) + e2##J)              \
                + q3 * (b2f((unsigned short)kv##J[3]) + e3##J);

#define EDGE_ACC(J)                                                         \
    den += ex##J;                                                           \
    a0 += ex##J * (b2f((unsigned short)vv##J[0]) + e0##J);                  \
    a1 += ex##J * (b2f((unsigned short)vv##J[1]) + e1##J);                  \
    a2 += ex##J * (b2f((unsigned short)vv##J[2]) + e2##J);                  \
    a3 += ex##J * (b2f((unsigned short)vv##J[3]) + e3##J);

#define AGG_CORE                                                            \
  float den = 0.f;                                                          \
  float a0 = 0.f, a1 = 0.f, a2 = 0.f, a3 = 0.f;                             \
  int p = s0;                                                               \
  for (; p + 4 <= s1; p += 4) {                                             \
    EDGE_LOAD(A, p)  EDGE_LOAD(B, p + 1)  EDGE_LOAD(C, p + 2)  EDGE_LOAD(D, p + 3) \
    dtA += __shfl_xor(dtA, 1);  dtB += __shfl_xor(dtB, 1);                  \
    dtC += __shfl_xor(dtC, 1);  dtD += __shfl_xor(dtD, 1);                  \
    dtA += __shfl_xor(dtA, 2);  dtB += __shfl_xor(dtB, 2);                  \
    dtC += __shfl_xor(dtC, 2);  dtD += __shfl_xor(dtD, 2);                  \
    dtA += __shfl_xor(dtA, 4);  dtB += __shfl_xor(dtB, 4);                  \
    dtC += __shfl_xor(dtC, 4);  dtD += __shfl_xor(dtD, 4);                  \
    dtA += __shfl_xor(dtA, 8);  dtB += __shfl_xor(dtB, 8);                  \
    dtC += __shfl_xor(dtC, 8);  dtD += __shfl_xor(dtD, 8);                  \
    dtA += __shfl_xor(dtA, 16); dtB += __shfl_xor(dtB, 16);                 \
    dtC += __shfl_xor(dtC, 16); dtD += __shfl_xor(dtD, 16);                 \
    float exA = __expf(dtA * INV_SQRT_C), exB = __expf(dtB * INV_SQRT_C);   \
    float exC = __expf(dtC * INV_SQRT_C), exD = __expf(dtD * INV_SQRT_C);   \
    EDGE_ACC(A) EDGE_ACC(B) EDGE_ACC(C) EDGE_ACC(D)                         \
  }                                                                         \
  for (; p < s1; ++p) {                                                     \
    EDGE_LOAD(T, p)                                                         \
    dtT += __shfl_xor(dtT, 1);                                              \
    dtT += __shfl_xor(dtT, 2);                                              \
    dtT += __shfl_xor(dtT, 4);                                              \
    dtT += __shfl_xor(dtT, 8);                                              \
    dtT += __shfl_xor(dtT, 16);                                             \
    float exT = __expf(dtT * INV_SQRT_C);                                   \
    EDGE_ACC(T)                                                             \
  }

// RMW variant (fallback): out already holds skip from node f32 job
__device__ __forceinline__ void process_dst(
    int d, int c0, const int* __restrict__ start, const unsigned short* __restrict__ esrc,
    const unsigned short* __restrict__ Q16, const unsigned short* __restrict__ K16,
    const unsigned short* __restrict__ V16, const unsigned short* __restrict__ e16,
    float* __restrict__ out)
{
  const int s0 = start[d], s1 = start[d + 1];
  if (s1 <= s0) return;
  s16x4 qv = *(const s16x4*)(Q16 + (size_t)d * 256 + c0);
  const float q0 = b2f((unsigned short)qv[0]), q1 = b2f((unsigned short)qv[1]);
  const float q2 = b2f((unsigned short)qv[2]), q3 = b2f((unsigned short)qv[3]);
  AGG_CORE
  float inv = 1.f / (den + 1e-16f);
  float4* op = (float4*)(out + (size_t)d * 256 + c0);
  float4 o = *op;
  o.x += a0 * inv; o.y += a1 * inv; o.z += a2 * inv; o.w += a3 * inv;
  *op = o;
}

// skip-add variant: out = S16[d] + attn (write-only out)
__device__ __forceinline__ void process_dst_skip(
    int d, int c0, const int* __restrict__ start, const unsigned short* __restrict__ esrc,
    const unsigned short* __restrict__ Q16, const unsigned short* __restrict__ K16,
    const unsigned short* __restrict__ V16, const unsigned short* __restrict__ e16,
    const unsigned short* __restrict__ S16, float* __restrict__ out)
{
  const int s0 = start[d], s1 = start[d + 1];
  s16x4 qv = *(const s16x4*)(Q16 + (size_t)d * 256 + c0);
  const float q0 = b2f((unsigned short)qv[0]), q1 = b2f((unsigned short)qv[1]);
  const float q2 = b2f((unsigned short)qv[2]), q3 = b2f((unsigned short)qv[3]);
  AGG_CORE
  float inv = 1.f / (den + 1e-16f);       // den==0 -> acc==0 -> 0*inv==0
  s16x4 sk = *(const s16x4*)(S16 + (size_t)d * 256 + c0);
  float4 o;
  o.x = b2f((unsigned short)sk[0]) + a0 * inv;
  o.y = b2f((unsigned short)sk[1]) + a1 * inv;
  o.z = b2f((unsigned short)sk[2]) + a2 * inv;
  o.w = b2f((unsigned short)sk[3]) + a3 * inv;
  *(float4*)(out + (size_t)d * 256 + c0) = o;
}

// ---------------- setup: prep_transpose + conv_x + csr_count fused ----------
__global__ __launch_bounds__(256) void setup_fused(
    WPtrs p, short* __restrict__ WtT,
    const float* __restrict__ xu, const float* __restrict__ xi,
    unsigned short* __restrict__ x16u, unsigned short* __restrict__ x16i, int nconv,
    const int* __restrict__ eia, const int* __restrict__ eib, int* __restrict__ counts)
{
  __shared__ short T[256 * 66];
  const int bx = blockIdx.x;
  const int tid = threadIdx.x;

  if (bx < NB_PREP) {
    const int wi = bx >> 2, cq = bx & 3;
    const float* w = p.w[wi];
    short* o = WtT + wi * 65536;
#pragma unroll
    for (int i = 0; i < 64; ++i) {
      int flat = tid + i * 256;
      int k = flat >> 6, cc = flat & 63;
      T[k * 66 + cc] = f2b(w[k * 256 + cq * 64 + cc]);
    }
    __syncthreads();
#pragma unroll
    for (int i = 0; i < 8; ++i) {
      int flat2 = tid + i * 256;
      int g = flat2 & 3, colb = (flat2 >> 2) & 15, ks = (flat2 >> 6) & 7, ctl = flat2 >> 9;
      int ct = cq * 4 + ctl;
      s16x8 v;
#pragma unroll
      for (int j = 0; j < 8; ++j)
        v[j] = T[(ks * 32 + g * 8 + j) * 66 + ctl * 16 + colb];
      *(s16x8*)(o + (((ct * 8 + ks) * 16 + colb) * 32 + g * 8)) = v;
    }
    return;
  }
  int cb = bx - NB_PREP;
  if (cb < nconv) {                    // conv_x
    int y = cb >= (nconv / 2);
    int xb = y ? cb - nconv / 2 : cb;
    const float* in = y ? xi : xu;
    unsigned short* out = y ? x16i : x16u;
    size_t base = ((size_t)xb * 256 + tid) * 8;
    float4 a = *(const float4*)(in + base);
    float4 b = *(const float4*)(in + base + 4);
    s16x8 v;
    v[0] = f2b(a.x); v[1] = f2b(a.y); v[2] = f2b(a.z); v[3] = f2b(a.w);
    v[4] = f2b(b.x); v[5] = f2b(b.y); v[6] = f2b(b.z); v[7] = f2b(b.w);
    *(s16x8*)(out + base) = v;
    return;
  }
  cb -= nconv;                         // csr_count
  int y = cb >= (NB_CNT / 2);
  int tb = y ? cb - NB_CNT / 2 : cb;
  const int* ei = y ? eib : eia;
  int* c = counts + y * N_NODES;
  int t = tb * 256 + tid;
  if (t < E_EDGES) atomicAdd(&c[ei[E_EDGES + t]], 1);
}

// ---------------- CSR scan (wide: 8 elems/thread, ~7 iterations) ----------
__global__ __launch_bounds__(1024) void csr_scan3(int* __restrict__ counts,
                                                  int* __restrict__ start) {
  int* cnt = counts + blockIdx.x * N_NODES;
  int* st  = start + blockIdx.x * (N_NODES + 1);
  __shared__ int wsum[16];
  __shared__ int chunk_tot;
  __shared__ int carry_s;
  const int tid = threadIdx.x, lane = tid & 63, wid = tid >> 6;
  if (tid == 0) carry_s = 0;
  __syncthreads();
  for (int base = 0; base < N_NODES; base += 8192) {
    int idx = base + tid * 8;
    int c[8];
#pragma unroll
    for (int j = 0; j < 8; ++j) c[j] = (idx + j < N_NODES) ? cnt[idx + j] : 0;
    int pre[8]; int run = 0;
#pragma unroll
    for (int j = 0; j < 8; ++j) { pre[j] = run; run += c[j]; }
    int v = run;                              // thread total
#pragma unroll
    for (int dd = 1; dd < 64; dd <<= 1) {
      int t = __shfl_up(v, dd);
      if (lane >= dd) v += t;
    }
    if (lane == 63) wsum[wid] = v;
    int wexcl = v - run;                      // exclusive within wave
    __syncthreads();
    if (tid == 0) {
      int r2 = 0;
#pragma unroll
      for (int i = 0; i < 16; ++i) { int t = wsum[i]; wsum[i] = r2; r2 += t; }
      chunk_tot = r2;
    }
    __syncthreads();
    int basev = carry_s + wsum[wid] + wexcl;
#pragma unroll
    for (int j = 0; j < 8; ++j)
      if (idx + j < N_NODES) { st[idx + j] = basev + pre[j]; cnt[idx + j] = basev + pre[j]; }
    __syncthreads();
    if (tid == 0) carry_s += chunk_tot;
  }
  if (tid == 0) st[N_NODES] = carry_s;
}

__global__ __launch_bounds__(256) void csr_fill2(const int* __restrict__ eia,
                                                 const int* __restrict__ eib,
                                                 int* __restrict__ counts,
                                                 int* __restrict__ pos,
                                                 unsigned short* __restrict__ esrc) {
  int t = blockIdx.x * 256 + threadIdx.x;
  const int* ei = blockIdx.y ? eib : eia;
  int* cur = counts + blockIdx.y * N_NODES;
  int* ps  = pos + blockIdx.y * E_EDGES;
  unsigned short* es = esrc + (size_t)blockIdx.y * E_EDGES;
  if (t < E_EDGES) {
    int d = ei[E_EDGES + t];
    int p = atomicAdd(&cur[d], 1);
    ps[t] = p;
    es[p] = (unsigned short)ei[t];
  }
}

// ---------------- fused node+edge: single type ----------------
struct FusedArgs { NodeSet n; EdgeSet e; const float* Wtim; const float* btim; int use16; };

__global__ __launch_bounds__(512) void fused_ne(FusedArgs A) {
  __shared__ __align__(16) char smem[34816];
  const int bx = blockIdx.x;
  int nb = -1, eb = -1;
  if (bx < NB_PAIR) { if (bx & 1) eb = bx >> 1; else nb = bx >> 1; }
  else nb = NB_EDGE + (bx - NB_PAIR);
  if (nb >= 0) node_block(smem, threadIdx.x, nb, A.n, A.use16);
  else         edge_block(smem, threadIdx.x, eb, A.e, A.Wtim, A.btim);
}

// ---------------- standalone aggregates (persistent waves) ----------
__global__ __launch_bounds__(256) void aggregate_fused5(
    const int* __restrict__ start, const unsigned short* __restrict__ esrc,
    const unsigned short* __restrict__ Q16, const unsigned short* __restrict__ K16,
    const unsigned short* __restrict__ V16, const unsigned short* __restrict__ e16,
    float* __restrict__ out)
{
  const int wave = blockIdx.x * 4 + (threadIdx.x >> 6);
  const int nwaves = gridDim.x * 4;
  const int c0 = (threadIdx.x & 63) * 4;
  for (int d = wave; d < N_NODES; d += nwaves)
    process_dst(d, c0, start, esrc, Q16, K16, V16, e16, out);
}

__global__ __launch_bounds__(256) void aggregate_skip(
    const int* __restrict__ start, const unsigned short* __restrict__ esrc,
    const unsigned short* __restrict__ Q16, const unsigned short* __restrict__ K16,
    const unsigned short* __restrict__ V16, const unsigned short* __restrict__ e16,
    const unsigned short* __restrict__ S16, float* __restrict__ out)
{
  const int wave = blockIdx.x * 4 + (threadIdx.x >> 6);
  const int nwaves = gridDim.x * 4;
  const int c0 = (threadIdx.x & 63) * 4;
  for (int d = wave; d < N_NODES; d += nwaves)
    process_dst_skip(d, c0, start, esrc, Q16, K16, V16, e16, S16, out);
}

extern "C" void kernel_launch(void* const* d_in, const int* in_sizes, int n_in,
                              void* d_out, int out_size, void* d_ws, size_t ws_size,
                              hipStream_t stream) {
  const float* x_user  = (const float*)d_in[0];
  const float* x_item  = (const float*)d_in[1];
  const float* lu_user = (const float*)d_in[2];
  const float* lu_item = (const float*)d_in[3];
  const int*   ei_a    = (const int*)d_in[4];
  const int*   ei_b    = (const int*)d_in[5];
  const float* t_a     = (const float*)d_in[6];
  const float* t_b     = (const float*)d_in[7];
  const float* msg_a   = (const float*)d_in[8];
  const float* msg_b   = (const float*)d_in[9];
  const float* W_t     = (const float*)d_in[10];
  const float* b_t     = (const float*)d_in[11];
  const float* Wq_a = (const float*)d_in[12]; const float* bq_a = (const float*)d_in[13];
  const float* Wk_a = (const float*)d_in[14]; const float* bk_a = (const float*)d_in[15];
  const float* Wv_a = (const float*)d_in[16]; const float* bv_a = (const float*)d_in[17];
  const float* We_a = (const float*)d_in[18];
  const float* Ws_a = (const float*)d_in[19]; const float* bs_a = (const float*)d_in[20];
  const float* Wq_b = (const float*)d_in[21]; const float* bq_b = (const float*)d_in[22];
  const float* Wk_b = (const float*)d_in[23]; const float* bk_b = (const float*)d_in[24];
  const float* Wv_b = (const float*)d_in[25]; const float* bv_b = (const float*)d_in[26];
  const float* We_b = (const float*)d_in[27];
  const float* Ws_b = (const float*)d_in[28]; const float* bs_b = (const float*)d_in[29];

  float* out_user = (float*)d_out;
  float* out_item = (float*)d_out + (size_t)N_NODES * 256;

  WPtrs wp;
  wp.w[0] = Wq_a; wp.w[1] = Wk_a; wp.w[2] = Wv_a; wp.w[3] = Ws_a; wp.w[4] = We_a;
  wp.w[5] = Wq_b; wp.w[6] = Wk_b; wp.w[7] = Wv_b; wp.w[8] = Ws_b; wp.w[9] = We_b;

  dim3 blk(256);
  dim3 blk512(512);
  dim3 gEt2((E_EDGES + 255) / 256, 2);

  // ws layout
  char* ws = (char*)d_ws;
  size_t off = 0;
  short* WtT = (short*)(ws + off); off += (size_t)10 * 65536 * 2;
  unsigned short* Q16 = (unsigned short*)(ws + off); off += (size_t)N_NODES * 256 * 2;
  unsigned short* K16 = (unsigned short*)(ws + off); off += (size_t)N_NODES * 256 * 2;
  unsigned short* V16 = (unsigned short*)(ws + off); off += (size_t)N_NODES * 256 * 2;
  unsigned short* e16 = (unsigned short*)(ws + off); off += (size_t)E_EDGES * 256 * 2;
  int* pos    = (int*)(ws + off); off += (size_t)2 * E_EDGES * 4;
  int* counts = (int*)(ws + off); off += (size_t)2 * N_NODES * 4;
  int* startb = (int*)(ws + off); off += (size_t)2 * (N_NODES + 1) * 4;
  unsigned short* esrc = (unsigned short*)(ws + off); off += (size_t)2 * E_EDGES * 2;
  const size_t off_base = off;
  unsigned short* X16u = (unsigned short*)(ws + off); off += (size_t)N_NODES * 256 * 2;
  unsigned short* X16i = (unsigned short*)(ws + off); off += (size_t)N_NODES * 256 * 2;
  const size_t off_t1 = off;
  unsigned short* S16 = (unsigned short*)(ws + off); off += (size_t)N_NODES * 256 * 2;
  const size_t off_skip = off;
  const bool use_x16  = (ws_size >= off_t1);
  const bool use_skip = (ws_size >= off_skip);
  if (!use_x16 && ws_size < off_base) return;   // fail loudly

  const int nconv = use_x16 ? NB_CONV : 0;

  hipMemsetAsync(counts, 0, (size_t)2 * N_NODES * 4, stream);
  setup_fused<<<dim3(NB_PREP + nconv + NB_CNT), blk, 0, stream>>>(
      wp, WtT, x_user, x_item, X16u, X16i, nconv, ei_a, ei_b, counts);
  csr_scan3<<<2, 1024, 0, stream>>>(counts, startb);
  csr_fill2<<<gEt2, blk, 0, stream>>>(ei_a, ei_b, counts, pos, esrc);

  // Build per-type sets
  NodeSet na, nb_;
  na.X16[0] = X16u; na.X16[1] = X16u; na.X16[2] = X16i; na.X16[3] = X16i;
  na.Xf[0] = x_user; na.Xf[1] = x_user; na.Xf[2] = x_item; na.Xf[3] = x_item;
  na.Wt[0] = WtT + 1 * 65536; na.Wt[1] = WtT + 2 * 65536;
  na.Wt[2] = WtT + 0 * 65536; na.Wt[3] = WtT + 3 * 65536;
  na.bias[0] = bk_a; na.bias[1] = bv_a; na.bias[2] = bq_a; na.bias[3] = bs_a;
  na.o16[0] = K16; na.o16[1] = V16; na.o16[2] = Q16;
  na.of[0] = nullptr; na.of[1] = nullptr; na.of[2] = nullptr;
  if (use_skip) { na.o16[3] = S16; na.of[3] = nullptr; }
  else          { na.o16[3] = nullptr; na.of[3] = out_item; }

  nb_.X16[0] = X16i; nb_.X16[1] = X16i; nb_.X16[2] = X16u; nb_.X16[3] = X16u;
  nb_.Xf[0] = x_item; nb_.Xf[1] = x_item; nb_.Xf[2] = x_user; nb_.Xf[3] = x_user;
  nb_.Wt[0] = WtT + 6 * 65536; nb_.Wt[1] = WtT + 7 * 65536;
  nb_.Wt[2] = WtT + 5 * 65536; nb_.Wt[3] = WtT + 8 * 65536;
  nb_.bias[0] = bk_b; nb_.bias[1] = bv_b; nb_.bias[2] = bq_b; nb_.bias[3] = bs_b;
  nb_.o16[0] = K16; nb_.o16[1] = V16; nb_.o16[2] = Q16;
  nb_.of[0] = nullptr; nb_.of[1] = nullptr; nb_.of[2] = nullptr;
  if (use_skip) { nb_.o16[3] = S16; nb_.of[3] = nullptr; }
  else          { nb_.o16[3] = nullptr; nb_.of[3] = out_user; }

  EdgeSet ea, eb_;
  ea.ei = ei_a; ea.tvec = t_a; ea.lu = lu_user; ea.msg = msg_a;
  ea.WeT = WtT + 4 * 65536; ea.pos = pos; ea.e16g = e16;
  eb_.ei = ei_b; eb_.tvec = t_b; eb_.lu = lu_item; eb_.msg = msg_b;
  eb_.WeT = WtT + 9 * 65536; eb_.pos = pos + E_EDGES; eb_.e16g = e16;

  const int u16 = use_x16 ? 1 : 0;

  // ---- type a: fused node+edge, then aggregate ----
  FusedArgs Aa; Aa.n = na; Aa.e = ea; Aa.Wtim = W_t; Aa.btim = b_t; Aa.use16 = u16;
  fused_ne<<<dim3(NB_FUSED), blk512, 0, stream>>>(Aa);
  if (use_skip)
    aggregate_skip<<<dim3(2048), blk, 0, stream>>>(startb, esrc, Q16, K16, V16, e16, S16, out_item);
  else
    aggregate_fused5<<<dim3(2048), blk, 0, stream>>>(startb, esrc, Q16, K16, V16, e16, out_item);

  // ---- type b ----
  FusedArgs Ab; Ab.n = nb_; Ab.e = eb_; Ab.Wtim = W_t; Ab.btim = b_t; Ab.use16 = u16;
  fused_ne<<<dim3(NB_FUSED), blk512, 0, stream>>>(Ab);
  if (use_skip)
    aggregate_skip<<<dim3(2048), blk, 0, stream>>>(startb + (N_NODES + 1), esrc + E_EDGES,
        Q16, K16, V16, e16, S16, out_user);
  else
    aggregate_fused5<<<dim3(2048), blk, 0, stream>>>(startb + (N_NODES + 1), esrc + E_EDGES,
        Q16, K16, V16, e16, out_user);
}